// Round 4
// baseline (202.255 us; speedup 1.0000x reference)
//
#include <hip/hip_runtime.h>

#define TPB 256

// Problem dims
constexpr int B_ = 4096, A_ = 11;
constexpr int R_ = B_ * A_;       // 45056 rows
constexpr int K32 = 32;           // L*IN folded input dim

// ws offsets (floats). MH2/BH2 alias regions dead after preC.
constexpr int M_O     = 0;        // 8192   folded through fc2 (32x256)
constexpr int M2_O    = 8192;     // 8192   folded through fc3 (32x256)
constexpr int WC_O    = 16384;    // 1024   W_in @ W_pos_top       [dead after preC]
constexpr int XB_O    = 19712;    // 2048   per-timestep bias      [dead after preC]
constexpr int CB_O    = 21760;    // 256
constexpr int B2_O    = 22016;    // 2816   per-agent bias (11x256)
constexpr int WN2L_O  = 24832;    // 4096   Wn2 @ W_line (64x64)
constexpr int MH1_O   = 28928;    // 2048   M2 @ Wh1 (32x64)
constexpr int BH1_O   = 30976;    // 704
constexpr int MH2_O   = 16384;    // 2048   (aliases WC, dead by preE)
constexpr int BH2_O   = 18432;    // 704    (unused region)
constexpr int U1_O    = 32768;    // u1, then agg1 after k_agg
constexpr int SZ_RH   = R_ * 64;  // 2883584
constexpr int V1_O    = U1_O + SZ_RH;
constexpr int U2_O    = V1_O + SZ_RH;  // u2, then agg2 after k_agg
constexpr int V2_O    = U2_O + SZ_RH;

// ================= pre kernels: wide split-K folds =================

__global__ __launch_bounds__(TPB) void k_preAB(const float* __restrict__ Win,
                                               const float* __restrict__ bin,
                                               const float* __restrict__ Wpos,
                                               const float* __restrict__ bpos,
                                               const float* __restrict__ Wn2,
                                               const float* __restrict__ Wline,
                                               float* __restrict__ ws) {
    __shared__ float red[8 * 33];
    const int t = threadIdx.x, o8 = t & 31, ks = t >> 5;
    const int bx = blockIdx.x;
    if (bx < 32) {                       // Wc[i][j], 1024 outs, K=256
        int o = bx * 32 + o8, i = o >> 8, j = o & 255;
        const float* Ar = Win + i * 256;
        float p = 0.f;
        #pragma unroll 8
        for (int d = ks * 32; d < ks * 32 + 32; ++d) p += Ar[d] * Wpos[d * 256 + j];
        red[ks * 33 + o8] = p;
        __syncthreads();
        if (t < 32) {
            float s = 0.f;
            #pragma unroll
            for (int m = 0; m < 8; ++m) s += red[m * 33 + t];
            ws[WC_O + bx * 32 + t] = s;
        }
    } else if (bx < 96) {                // xb[l][j], 2048 outs, K=512 (bin then pe inline)
        int o = (bx - 32) * 32 + o8, l = o >> 8, j = o & 255;
        const float c0 = -logf(10000.f) / 256.f;
        float p = 0.f;
        for (int d = ks * 64; d < ks * 64 + 64; ++d) {
            float a;
            if (d < 256) a = bin[d];
            else {
                int dd = d - 256;
                float freq = expf((float)(dd & ~1) * c0);
                float ang = (float)l * freq;
                a = (dd & 1) ? cosf(ang) : sinf(ang);
            }
            p += a * Wpos[d * 256 + j];
        }
        red[ks * 33 + o8] = p;
        __syncthreads();
        if (t < 32) {
            int oo = (bx - 32) * 32 + t;
            float s = bpos[oo & 255];
            #pragma unroll
            for (int m = 0; m < 8; ++m) s += red[m * 33 + t];
            ws[XB_O + oo] = s;
        }
    } else {                             // Wn2L = Wn2 @ W_line, 4096 outs, 128 blocks
        int o = (bx - 96) * 32 + o8, k = o >> 6, c = o & 63;
        const float* Ar = Wn2 + k * 256;
        float p = 0.f;
        #pragma unroll 8
        for (int d = ks * 32; d < ks * 32 + 32; ++d) p += Ar[d] * Wline[d * 64 + c];
        red[ks * 33 + o8] = p;
        __syncthreads();
        if (t < 32) {
            float s = 0.f;
            #pragma unroll
            for (int m = 0; m < 8; ++m) s += red[m * 33 + t];
            ws[WN2L_O + (bx - 96) * 32 + t] = s;
        }
    }
}

__global__ __launch_bounds__(TPB) void k_preC(const float* __restrict__ Wfc2,
                                              const float* __restrict__ bfc2,
                                              float* __restrict__ ws) {
    __shared__ float red[8 * 33];
    const int t = threadIdx.x, o8 = t & 31, ks = t >> 5;
    const int bx = blockIdx.x;
    if (bx < 256) {                      // M[k][j], 8192 outs, K=256; k=(l,i)
        int o = bx * 32 + o8, k = o >> 8, j = o & 255;
        int l = k >> 2, i = k & 3;
        const float* Ar = ws + WC_O + i * 256;
        const float* Br = Wfc2 + l * 65536 + j;
        float p = 0.f;
        #pragma unroll 8
        for (int d = ks * 32; d < ks * 32 + 32; ++d) p += Ar[d] * Br[d * 256];
        red[ks * 33 + o8] = p;
        __syncthreads();
        if (t < 32) {
            float s = 0.f;
            #pragma unroll
            for (int m = 0; m < 8; ++m) s += red[m * 33 + t];
            ws[M_O + bx * 32 + t] = s;
        }
    } else {                             // cb[j], 256 outs, K=2048
        int j = (bx - 256) * 32 + o8;
        const float* Ar = ws + XB_O;
        float p = 0.f;
        #pragma unroll 4
        for (int dk = ks * 256; dk < ks * 256 + 256; ++dk) p += Ar[dk] * Wfc2[dk * 256 + j];
        red[ks * 33 + o8] = p;
        __syncthreads();
        if (t < 32) {
            int jj = (bx - 256) * 32 + t;
            float s = bfc2[jj];
            #pragma unroll
            for (int m = 0; m < 8; ++m) s += red[m * 33 + t];
            ws[CB_O + jj] = s;
        }
    }
}

__global__ __launch_bounds__(TPB) void k_preD(const float* __restrict__ Wfc3,
                                              const float* __restrict__ bfc3,
                                              float* __restrict__ ws) {
    __shared__ float red[8 * 33];
    const int t = threadIdx.x, o8 = t & 31, ks = t >> 5;
    const int bx = blockIdx.x;
    if (bx < 256) {                      // M2 = M @ Wfc3_top, 8192 outs
        int o = bx * 32 + o8, k = o >> 8, j = o & 255;
        const float* Ar = ws + M_O + k * 256;
        float p = 0.f;
        #pragma unroll 8
        for (int d = ks * 32; d < ks * 32 + 32; ++d) p += Ar[d] * Wfc3[d * 256 + j];
        red[ks * 33 + o8] = p;
        __syncthreads();
        if (t < 32) {
            float s = 0.f;
            #pragma unroll
            for (int m = 0; m < 8; ++m) s += red[m * 33 + t];
            ws[M2_O + bx * 32 + t] = s;
        }
    } else {                             // bias2[a][j], 2816 outs (88 blocks)
        int o = (bx - 256) * 32 + o8, j = o & 255;
        const float* Ar = ws + CB_O;
        float p = 0.f;
        #pragma unroll 8
        for (int d = ks * 32; d < ks * 32 + 32; ++d) p += Ar[d] * Wfc3[d * 256 + j];
        red[ks * 33 + o8] = p;
        __syncthreads();
        if (t < 32) {
            int oo = (bx - 256) * 32 + t;
            int aa = oo >> 8, jj = oo & 255;
            float s = bfc3[jj] + Wfc3[(256 + aa) * 256 + jj];
            #pragma unroll
            for (int m = 0; m < 8; ++m) s += red[m * 33 + t];
            ws[B2_O + oo] = s;
        }
    }
}

__global__ __launch_bounds__(TPB) void k_preE(const float* __restrict__ Wh1,
                                              const float* __restrict__ Wh2,
                                              float* __restrict__ ws) {
    __shared__ float red[8 * 33];
    const int t = threadIdx.x, o8 = t & 31, ks = t >> 5;
    const int bx = blockIdx.x;
    const float* Bw;  int oo_base;  int out_o;  int mode;
    if (bx < 64)       { mode = 0; out_o = MH1_O; oo_base = bx * 32;         Bw = Wh1; }
    else if (bx < 86)  { mode = 1; out_o = BH1_O; oo_base = (bx - 64) * 32;  Bw = Wh1; }
    else if (bx < 150) { mode = 0; out_o = MH2_O; oo_base = (bx - 86) * 32;  Bw = Wh2; }
    else               { mode = 1; out_o = BH2_O; oo_base = (bx - 150) * 32; Bw = Wh2; }
    int o = oo_base + o8;
    int r = o >> 6, c = o & 63;
    const float* Aw = ws + (mode == 0 ? M2_O : B2_O) + r * 256;
    float p = 0.f;
    #pragma unroll 8
    for (int d = ks * 32; d < ks * 32 + 32; ++d) p += Aw[d] * Bw[d * 64 + c];
    red[ks * 33 + o8] = p;
    __syncthreads();
    if (t < 32) {
        float s = 0.f;
        #pragma unroll
        for (int m = 0; m < 8; ++m) s += red[m * 33 + t];
        ws[out_o + oo_base + t] = s;
    }
}

// ================= k_rows3: ftraj + h + u/v, LDS-B GEMM, 64 rows/block =================
// A-tiles padded (stride 36 / 68) -> broadcast ds_read_b128 conflict-free.

__global__ __launch_bounds__(TPB) void k_rows3(const float* __restrict__ in,
                                               const float* __restrict__ We1g,
                                               const float* __restrict__ We2g,
                                               float* __restrict__ ws,
                                               float* __restrict__ out) {
    __shared__ float inS[64 * 36];   // 9.2 KB
    __shared__ float hS[64 * 68];    // 17.4 KB
    __shared__ float Bs[2048];       // 8 KB staging
    const int t = threadIdx.x;
    const int rowBase = blockIdx.x * 64;
    const int tg = t >> 4, tc = t & 15;
    const int r0 = tg * 4, c0 = tc * 4;

    {   // stage input rows (coalesced float4, padded rows)
        const float4* src = (const float4*)(in + (size_t)rowBase * K32);
        #pragma unroll
        for (int o = t; o < 512; o += TPB) {
            int row = o >> 3, c4 = o & 7;
            *(float4*)&inS[row * 36 + c4 * 4] = src[o];
        }
    }
    __syncthreads();

    int ag[4];
    #pragma unroll
    for (int r = 0; r < 4; ++r) ag[r] = (rowBase + r0 + r) % 11;

    // ---- ftraj = in @ M2 + bias2 -> out[:,0:256]; tile 4r x 16c, M2 in 8-row chunks ----
    {
        float acc[4][16];
        #pragma unroll
        for (int r = 0; r < 4; ++r)
            #pragma unroll
            for (int c = 0; c < 16; ++c) acc[r][c] = 0.f;
        for (int kh = 0; kh < 4; ++kh) {
            if (kh) __syncthreads();
            {
                const float4* src = (const float4*)(ws + M2_O + kh * 2048);
                float4* dst = (float4*)Bs;
                dst[t] = src[t];
                dst[t + 256] = src[t + 256];
            }
            __syncthreads();
            #pragma unroll
            for (int kq = 0; kq < 2; ++kq) {
                float avq[4][4];
                #pragma unroll
                for (int r = 0; r < 4; ++r) {
                    float4 a4 = *(const float4*)&inS[(r0 + r) * 36 + kh * 8 + kq * 4];
                    avq[r][0] = a4.x; avq[r][1] = a4.y; avq[r][2] = a4.z; avq[r][3] = a4.w;
                }
                #pragma unroll
                for (int kk = 0; kk < 4; ++kk) {
                    float4 b[4];
                    #pragma unroll
                    for (int j = 0; j < 4; ++j)
                        b[j] = *(const float4*)&Bs[(kq * 4 + kk) * 256 + tc * 16 + j * 4];
                    #pragma unroll
                    for (int r = 0; r < 4; ++r) {
                        float a = avq[r][kk];
                        #pragma unroll
                        for (int j = 0; j < 4; ++j) {
                            acc[r][j * 4 + 0] += a * b[j].x;
                            acc[r][j * 4 + 1] += a * b[j].y;
                            acc[r][j * 4 + 2] += a * b[j].z;
                            acc[r][j * 4 + 3] += a * b[j].w;
                        }
                    }
                }
            }
        }
        #pragma unroll
        for (int r = 0; r < 4; ++r) {
            size_t ob = (size_t)(rowBase + r0 + r) * 576 + tc * 16;
            const float* bb = ws + B2_O + ag[r] * 256 + tc * 16;
            #pragma unroll
            for (int j = 0; j < 4; ++j) {
                float4 b = *(const float4*)&bb[j * 4];
                *(float4*)&out[ob + j * 4] =
                    make_float4(acc[r][j * 4 + 0] + b.x, acc[r][j * 4 + 1] + b.y,
                                acc[r][j * 4 + 2] + b.z, acc[r][j * 4 + 3] + b.w);
            }
        }
    }

    // ---- two NMP stages ----
    for (int s = 0; s < 2; ++s) {
        const int mh_o = s ? MH2_O : MH1_O;
        const int bh_o = s ? BH2_O : BH1_O;
        const float* We = s ? We2g : We1g;
        float* ug = ws + (s ? U2_O : U1_O);
        float* vg = ws + (s ? V2_O : V1_O);

        __syncthreads();   // prior Bs / hS reads complete
        {   // stage Mh_s (2048 floats)
            const float4* src = (const float4*)(ws + mh_o);
            float4* dst = (float4*)Bs;
            dst[t] = src[t];
            dst[t + 256] = src[t + 256];
        }
        __syncthreads();
        // h = relu(in @ Mh + bh)
        float hacc[4][4];
        #pragma unroll
        for (int r = 0; r < 4; ++r)
            #pragma unroll
            for (int c = 0; c < 4; ++c) hacc[r][c] = 0.f;
        #pragma unroll
        for (int kq = 0; kq < 8; ++kq) {
            float avq[4][4];
            #pragma unroll
            for (int r = 0; r < 4; ++r) {
                float4 a4 = *(const float4*)&inS[(r0 + r) * 36 + kq * 4];
                avq[r][0] = a4.x; avq[r][1] = a4.y; avq[r][2] = a4.z; avq[r][3] = a4.w;
            }
            #pragma unroll
            for (int kk = 0; kk < 4; ++kk) {
                float4 b = *(const float4*)&Bs[(kq * 4 + kk) * 64 + c0];
                #pragma unroll
                for (int r = 0; r < 4; ++r) {
                    float a = avq[r][kk];
                    hacc[r][0] += a * b.x; hacc[r][1] += a * b.y;
                    hacc[r][2] += a * b.z; hacc[r][3] += a * b.w;
                }
            }
        }
        #pragma unroll
        for (int r = 0; r < 4; ++r) {
            float4 b = *(const float4*)&ws[bh_o + ag[r] * 64 + c0];
            float4 h = make_float4(fmaxf(hacc[r][0] + b.x, 0.f), fmaxf(hacc[r][1] + b.y, 0.f),
                                   fmaxf(hacc[r][2] + b.z, 0.f), fmaxf(hacc[r][3] + b.w, 0.f));
            *(float4*)&hS[(r0 + r) * 68 + c0] = h;
        }
        __syncthreads();   // hS ready; Mh reads done

        // u = h @ We[0:64], v = h @ We[64:128]; We in 16-row chunks (top+bot)
        float ua[4][4], va[4][4];
        #pragma unroll
        for (int r = 0; r < 4; ++r)
            #pragma unroll
            for (int c = 0; c < 4; ++c) { ua[r][c] = 0.f; va[r][c] = 0.f; }
        for (int kh = 0; kh < 4; ++kh) {
            if (kh) __syncthreads();
            {
                const float4* s0 = (const float4*)(We + kh * 1024);
                const float4* s1 = (const float4*)(We + 4096 + kh * 1024);
                float4* dst = (float4*)Bs;
                dst[t] = s0[t];
                dst[t + 256] = s1[t];
            }
            __syncthreads();
            #pragma unroll
            for (int kq = 0; kq < 4; ++kq) {
                float avq[4][4];
                #pragma unroll
                for (int r = 0; r < 4; ++r) {
                    float4 a4 = *(const float4*)&hS[(r0 + r) * 68 + kh * 16 + kq * 4];
                    avq[r][0] = a4.x; avq[r][1] = a4.y; avq[r][2] = a4.z; avq[r][3] = a4.w;
                }
                #pragma unroll
                for (int kk = 0; kk < 4; ++kk) {
                    float4 bu = *(const float4*)&Bs[(kq * 4 + kk) * 64 + c0];
                    float4 bv = *(const float4*)&Bs[1024 + (kq * 4 + kk) * 64 + c0];
                    #pragma unroll
                    for (int r = 0; r < 4; ++r) {
                        float a = avq[r][kk];
                        ua[r][0] += a * bu.x; ua[r][1] += a * bu.y;
                        ua[r][2] += a * bu.z; ua[r][3] += a * bu.w;
                        va[r][0] += a * bv.x; va[r][1] += a * bv.y;
                        va[r][2] += a * bv.z; va[r][3] += a * bv.w;
                    }
                }
            }
        }
        #pragma unroll
        for (int r = 0; r < 4; ++r) {
            size_t rb = (size_t)(rowBase + r0 + r) * 64 + c0;
            *(float4*)&ug[rb] = make_float4(ua[r][0], ua[r][1], ua[r][2], ua[r][3]);
            *(float4*)&vg[rb] = make_float4(va[r][0], va[r][1], va[r][2], va[r][3]);
        }
    }
}

// ================= k_agg: corr/thr + aggregation only (no big arrays) =================

__global__ __launch_bounds__(TPB) void k_agg(const float* __restrict__ out_ft,
                                             float* __restrict__ ws) {
    __shared__ float ftS[11 * 260];
    __shared__ float u1s[704], v1s[704], u2s[704], v2s[704];
    __shared__ float pd[256];
    __shared__ float dots[121];
    __shared__ float corrv[121];
    __shared__ float red[4];
    __shared__ float sthr;
    const int t = threadIdx.x;
    const int base = blockIdx.x * 11;

    for (int o = t; o < 704; o += TPB) {
        int row = o >> 6, c4 = o & 63;
        ((float4*)ftS)[row * 65 + c4] =
            *(const float4*)&out_ft[(size_t)(base + row) * 576 + c4 * 4];
    }
    if (t < 176) {
        ((float4*)u1s)[t] = ((const float4*)(ws + U1_O + (size_t)base * 64))[t];
        ((float4*)v1s)[t] = ((const float4*)(ws + V1_O + (size_t)base * 64))[t];
        ((float4*)u2s)[t] = ((const float4*)(ws + U2_O + (size_t)base * 64))[t];
        ((float4*)v2s)[t] = ((const float4*)(ws + V2_O + (size_t)base * 64))[t];
    }
    __syncthreads();

    // dots, 2-way split-K
    {
        float part = 0.f;
        int p = t >> 1, hf = t & 1;
        if (p < 121) {
            int i = p / 11, j = p - i * 11;
            const float* ra = &ftS[i * 260 + hf * 128];
            const float* rb = &ftS[j * 260 + hf * 128];
            #pragma unroll 8
            for (int dc = 0; dc < 32; ++dc) {
                float4 a = *(const float4*)&ra[dc * 4];
                float4 b = *(const float4*)&rb[dc * 4];
                part += a.x * b.x + a.y * b.y + a.z * b.z + a.w * b.w;
            }
        }
        pd[t] = part;
    }
    __syncthreads();
    if (t < 121) dots[t] = pd[2 * t] + pd[2 * t + 1];
    __syncthreads();
    if (t < 121) {
        int i = t / 11, j = t - i * 11;
        corrv[t] = dots[t] * rsqrtf(dots[i * 11 + i] * dots[j * 11 + j]);
    }
    __syncthreads();
    float v = (t < 121) ? corrv[t] : 3.0e38f;
    for (int off = 32; off > 0; off >>= 1) v = fminf(v, __shfl_down(v, off));
    if ((t & 63) == 0) red[t >> 6] = v;
    __syncthreads();
    if (t == 0) {
        float a = fminf(fminf(red[0], red[1]), fminf(red[2], red[3]));
        sthr = (a < 0.4f) ? 0.4f : ((a > 0.4f && a < 0.6f) ? a + 0.1f : a + 0.03f);
    }
    __syncthreads();
    const float thr = sthr;

    const int c = t & 63, g = t >> 6;
    const int nr = (g == 3) ? 2 : 3;
    float u1[3], u2[3], s1[3], s2[3], cnt[3];
    #pragma unroll
    for (int r = 0; r < 3; ++r) { s1[r] = 0.f; s2[r] = 0.f; cnt[r] = 0.f; }
    for (int r = 0; r < nr; ++r) {
        u1[r] = u1s[(g + 4 * r) * 64 + c];
        u2[r] = u2s[(g + 4 * r) * 64 + c];
    }
    #pragma unroll
    for (int j = 0; j < 11; ++j) {
        float vv1 = v1s[j * 64 + c];
        float vv2 = v2s[j * 64 + c];
        for (int r = 0; r < nr; ++r) {
            float cw = corrv[(g + 4 * r) * 11 + j];
            s1[r] += fmaxf(u1[r] + vv1, 0.f);
            float adj = (cw >= thr) ? 1.f : 0.f;
            s2[r] += adj * fmaxf(u2[r] + vv2, 0.f);
            cnt[r] += adj;
        }
    }
    for (int r = 0; r < nr; ++r) {
        ws[U1_O + (size_t)(base + g + 4 * r) * 64 + c] = s1[r] * (1.f / 11.f);
        ws[U2_O + (size_t)(base + g + 4 * r) * 64 + c] = s2[r] / (cnt[r] + 1e-6f);
    }
}

// ================= k_tail2: inter = agg1@Wn1, feat = agg2@Wn2L (register-tiled) =================

__global__ __launch_bounds__(TPB) void k_tail2(const float* __restrict__ Wn1,
                                               const float* __restrict__ ws,
                                               float* __restrict__ out) {
    __shared__ float aS[64 * 68];    // 17.4 KB, reused agg1 then agg2
    __shared__ float Bs[2048];       // 8 KB
    const int t = threadIdx.x;
    const int rowBase = blockIdx.x * 64;
    const int tg = t >> 4, tc = t & 15;
    const int r0 = tg * 4, c0 = tc * 4;

    {   // stage agg1 (padded rows)
        const float4* s1 = (const float4*)(ws + U1_O + (size_t)rowBase * 64);
        #pragma unroll
        for (int o = t; o < 1024; o += TPB) {
            int row = o >> 4, c4 = o & 15;
            *(float4*)&aS[row * 68 + c4 * 4] = s1[o];
        }
    }
    __syncthreads();

    // ---- inter = agg1 @ Wn1 (K=64), Wn1 in 8-row chunks ----
    {
        float acc[4][16];
        #pragma unroll
        for (int r = 0; r < 4; ++r)
            #pragma unroll
            for (int c = 0; c < 16; ++c) acc[r][c] = 0.f;
        for (int kh = 0; kh < 8; ++kh) {
            if (kh) __syncthreads();
            {
                const float4* src = (const float4*)(Wn1 + kh * 2048);
                float4* dst = (float4*)Bs;
                dst[t] = src[t];
                dst[t + 256] = src[t + 256];
            }
            __syncthreads();
            #pragma unroll
            for (int kq = 0; kq < 2; ++kq) {
                float avq[4][4];
                #pragma unroll
                for (int r = 0; r < 4; ++r) {
                    float4 a4 = *(const float4*)&aS[(r0 + r) * 68 + kh * 8 + kq * 4];
                    avq[r][0] = a4.x; avq[r][1] = a4.y; avq[r][2] = a4.z; avq[r][3] = a4.w;
                }
                #pragma unroll
                for (int kk = 0; kk < 4; ++kk) {
                    float4 b[4];
                    #pragma unroll
                    for (int j = 0; j < 4; ++j)
                        b[j] = *(const float4*)&Bs[(kq * 4 + kk) * 256 + tc * 16 + j * 4];
                    #pragma unroll
                    for (int r = 0; r < 4; ++r) {
                        float a = avq[r][kk];
                        #pragma unroll
                        for (int j = 0; j < 4; ++j) {
                            acc[r][j * 4 + 0] += a * b[j].x;
                            acc[r][j * 4 + 1] += a * b[j].y;
                            acc[r][j * 4 + 2] += a * b[j].z;
                            acc[r][j * 4 + 3] += a * b[j].w;
                        }
                    }
                }
            }
        }
        #pragma unroll
        for (int r = 0; r < 4; ++r) {
            size_t ob = (size_t)(rowBase + r0 + r) * 576 + 256 + tc * 16;
            #pragma unroll
            for (int j = 0; j < 4; ++j)
                *(float4*)&out[ob + j * 4] = make_float4(acc[r][j * 4 + 0], acc[r][j * 4 + 1],
                                                         acc[r][j * 4 + 2], acc[r][j * 4 + 3]);
        }
    }

    __syncthreads();   // inter's aS & Bs reads done
    {   // restage aS with agg2
        const float4* s2 = (const float4*)(ws + U2_O + (size_t)rowBase * 64);
        #pragma unroll
        for (int o = t; o < 1024; o += TPB) {
            int row = o >> 4, c4 = o & 15;
            *(float4*)&aS[row * 68 + c4 * 4] = s2[o];
        }
    }
    // ---- feat = agg2 @ Wn2L (K=64), Wn2L in 2 chunks of 32 rows ----
    {
        float fa[4][4];
        #pragma unroll
        for (int r = 0; r < 4; ++r)
            #pragma unroll
            for (int c = 0; c < 4; ++c) fa[r][c] = 0.f;
        for (int kh = 0; kh < 2; ++kh) {
            __syncthreads();
            {
                const float4* src = (const float4*)(ws + WN2L_O + kh * 2048);
                float4* dst = (float4*)Bs;
                dst[t] = src[t];
                dst[t + 256] = src[t + 256];
            }
            __syncthreads();
            #pragma unroll
            for (int kq = 0; kq < 8; ++kq) {
                float avq[4][4];
                #pragma unroll
                for (int r = 0; r < 4; ++r) {
                    float4 a4 = *(const float4*)&aS[(r0 + r) * 68 + kh * 32 + kq * 4];
                    avq[r][0] = a4.x; avq[r][1] = a4.y; avq[r][2] = a4.z; avq[r][3] = a4.w;
                }
                #pragma unroll
                for (int kk = 0; kk < 4; ++kk) {
                    float4 b = *(const float4*)&Bs[(kq * 4 + kk) * 64 + c0];
                    #pragma unroll
                    for (int r = 0; r < 4; ++r) {
                        float a = avq[r][kk];
                        fa[r][0] += a * b.x; fa[r][1] += a * b.y;
                        fa[r][2] += a * b.z; fa[r][3] += a * b.w;
                    }
                }
            }
        }
        #pragma unroll
        for (int r = 0; r < 4; ++r)
            *(float4*)&out[(size_t)(rowBase + r0 + r) * 576 + 512 + c0] =
                make_float4(fa[r][0], fa[r][1], fa[r][2], fa[r][3]);
    }
}

extern "C" void kernel_launch(void* const* d_in, const int* in_sizes, int n_in,
                              void* d_out, int out_size, void* d_ws, size_t ws_size,
                              hipStream_t stream) {
    (void)in_sizes; (void)n_in; (void)out_size; (void)ws_size;
    const float* in     = (const float*)d_in[0];
    const float* W_in   = (const float*)d_in[1];
    const float* b_in   = (const float*)d_in[2];
    const float* W_pos  = (const float*)d_in[3];
    const float* b_pos  = (const float*)d_in[4];
    const float* W_fc2  = (const float*)d_in[5];
    const float* b_fc2  = (const float*)d_in[6];
    const float* W_fc3  = (const float*)d_in[7];
    const float* b_fc3  = (const float*)d_in[8];
    const float* Wh1    = (const float*)d_in[9];
    const float* We1    = (const float*)d_in[10];
    const float* Wn1    = (const float*)d_in[11];
    const float* Wh2    = (const float*)d_in[12];
    const float* We2    = (const float*)d_in[13];
    const float* Wn2    = (const float*)d_in[14];
    const float* W_line = (const float*)d_in[15];
    float* out = (float*)d_out;
    float* ws  = (float*)d_ws;

    k_preAB<<<224, TPB, 0, stream>>>(W_in, b_in, W_pos, b_pos, Wn2, W_line, ws);
    k_preC<<<264, TPB, 0, stream>>>(W_fc2, b_fc2, ws);
    k_preD<<<344, TPB, 0, stream>>>(W_fc3, b_fc3, ws);
    k_preE<<<172, TPB, 0, stream>>>(Wh1, Wh2, ws);
    k_rows3<<<R_ / 64, TPB, 0, stream>>>(in, We1, We2, ws, out);
    k_agg<<<B_, TPB, 0, stream>>>(out, ws);
    k_tail2<<<R_ / 64, TPB, 0, stream>>>(Wn1, ws, out);
}